// Round 1
// baseline (359.089 us; speedup 1.0000x reference)
//
#include <hip/hip_runtime.h>

typedef _Float16 half8 __attribute__((ext_vector_type(8)));
typedef float f32x4 __attribute__((ext_vector_type(4)));

#define ROWS 64
#define HA_PITCH 168   // 128 h + 6 x + 1 one + 25 zero + 8 pad (fp16), row stride 336 B (16B aligned)
#define A1_PITCH 136   // 128 + 8 pad

__device__ __forceinline__ float fast_sigmoid(float x) {
    float e = __builtin_amdgcn_exp2f(-1.442695041f * x);
    return __builtin_amdgcn_rcpf(1.0f + e);
}
__device__ __forceinline__ float fast_tanh(float x) {
    float ax = __builtin_fabsf(x);
    float e = __builtin_amdgcn_exp2f(-2.885390082f * ax);
    float t = (1.0f - e) * __builtin_amdgcn_rcpf(1.0f + e);
    return __builtin_copysignf(t, x);
}

#define MFMA(a, b, c) __builtin_amdgcn_mfma_f32_16x16x32_f16((a), (b), (c), 0, 0, 0)

__global__ __launch_bounds__(256, 1)
void traj_gru(const float* __restrict__ history,
              const float* __restrict__ w_ih, const float* __restrict__ w_hh,
              const float* __restrict__ b_ih, const float* __restrict__ b_hh,
              const float* __restrict__ w1, const float* __restrict__ b1,
              const float* __restrict__ w2, const float* __restrict__ b2,
              float* __restrict__ out)
{
    __shared__ __align__(16) _Float16 h_aug[ROWS * HA_PITCH];
    __shared__ __align__(16) _Float16 a1s[ROWS * A1_PITCH];

    const int tid  = threadIdx.x;
    const int wave = tid >> 6;
    const int lane = tid & 63;
    const int ln16 = lane & 15;
    const int q    = lane >> 4;      // 0..3 quad within wave
    const int rowbase = blockIdx.x * ROWS;
    const int cbase = wave * 32;     // this wave's h-column base (32 cols per wave)

    // ---- init LDS: h = 0, x slots = 0, col 134 = 1.0 (bias lane for the x K-tile) ----
    for (int idx = tid; idx < ROWS * HA_PITCH; idx += 256) {
        int col = idx % HA_PITCH;
        h_aug[idx] = (col == 134) ? (_Float16)1.0f : (_Float16)0.0f;
    }

    // ---- persistent B fragments in registers ----
    // gh = h @ w_hh^T : B[k][n] = w_hh[n][k]; lane holds n=base+ln16, k=kt*32+q*8+j
    half8 Bh[3][2][4];   // [gate r/z/n][col subtile][ktile]
    #pragma unroll
    for (int g = 0; g < 3; ++g)
      #pragma unroll
      for (int s = 0; s < 2; ++s)
        #pragma unroll
        for (int kt = 0; kt < 4; ++kt) {
            int n = g * 128 + cbase + s * 16 + ln16;
            const float* p = w_hh + n * 128 + kt * 32 + q * 8;
            half8 v;
            #pragma unroll
            for (int j = 0; j < 8; ++j) v[j] = (_Float16)p[j];
            Bh[g][s][kt] = v;
        }

    // gi via x K-tile: A_x = [x0..x5, 1, 0...]; B rows: k<6 -> w_ih[n][k], k==6 -> bias, else 0
    half8 Bi[3][2];
    #pragma unroll
    for (int g = 0; g < 3; ++g)
      #pragma unroll
      for (int s = 0; s < 2; ++s) {
        int n = g * 128 + cbase + s * 16 + ln16;
        half8 v;
        #pragma unroll
        for (int j = 0; j < 8; ++j) v[j] = (_Float16)0.0f;
        if (q == 0) {
            #pragma unroll
            for (int j = 0; j < 6; ++j) v[j] = (_Float16)w_ih[n * 6 + j];
            float bias = b_ih[n] + (g < 2 ? b_hh[n] : 0.0f); // r,z: fold both biases; n: b_ih only
            v[6] = (_Float16)bias;
        }
        Bi[g][s] = v;
      }

    float bhn[2], b1r[2];
    #pragma unroll
    for (int s = 0; s < 2; ++s) {
        bhn[s] = b_hh[256 + cbase + s * 16 + ln16];  // b_hh for n gate (kept separate: r*h_n)
        b1r[s] = b1[cbase + s * 16 + ln16];
    }

    half8 Bw1[2][4];   // a1 = h @ w1^T
    #pragma unroll
    for (int s = 0; s < 2; ++s)
      #pragma unroll
      for (int kt = 0; kt < 4; ++kt) {
        int n = cbase + s * 16 + ln16;
        const float* p = w1 + n * 128 + kt * 32 + q * 8;
        half8 v;
        #pragma unroll
        for (int j = 0; j < 8; ++j) v[j] = (_Float16)p[j];
        Bw1[s][kt] = v;
      }

    half8 Bw2[4];      // out = a1 @ w2^T, only n<6 valid
    #pragma unroll
    for (int kt = 0; kt < 4; ++kt) {
        half8 v;
        #pragma unroll
        for (int j = 0; j < 8; ++j) v[j] = (_Float16)0.0f;
        if (ln16 < 6) {
            const float* p = w2 + ln16 * 128 + kt * 32 + q * 8;
            #pragma unroll
            for (int j = 0; j < 8; ++j) v[j] = (_Float16)p[j];
        }
        Bw2[kt] = v;
    }
    float b2r = (ln16 < 6) ? b2[ln16] : 0.0f;

    float hp[4][2][4] = {};  // h_prev in regs; C-layout position is step-invariant

    __syncthreads();

    // x_0 = history[:, 0]
    for (int idx = tid; idx < ROWS * 6; idx += 256) {
        int r = idx / 6, c = idx - r * 6;
        h_aug[r * HA_PITCH + 128 + c] = (_Float16)history[(rowbase + r) * 300 + c];
    }
    __syncthreads();

    auto gru_step = [&](int next_t) {
        // A-fragment reads (h K-tiles 0..3 + x K-tile) into regs, then barrier
        half8 Ah[4][4], Ax[4];
        #pragma unroll
        for (int mt = 0; mt < 4; ++mt) {
            const _Float16* rp = &h_aug[(mt * 16 + ln16) * HA_PITCH];
            #pragma unroll
            for (int kt = 0; kt < 4; ++kt)
                Ah[mt][kt] = *(const half8*)(rp + kt * 32 + q * 8);
            Ax[mt] = *(const half8*)(rp + 128 + q * 8);
        }
        __syncthreads();  // all reads done before any wave writes h_new

        #pragma unroll
        for (int mt = 0; mt < 4; ++mt)
          #pragma unroll
          for (int s = 0; s < 2; ++s) {
            f32x4 ar = {0,0,0,0}, az = {0,0,0,0}, ahn = {0,0,0,0}, ain = {0,0,0,0};
            #pragma unroll
            for (int kt = 0; kt < 4; ++kt) {
                ar  = MFMA(Ah[mt][kt], Bh[0][s][kt], ar);
                az  = MFMA(Ah[mt][kt], Bh[1][s][kt], az);
                ahn = MFMA(Ah[mt][kt], Bh[2][s][kt], ahn);
            }
            ar  = MFMA(Ax[mt], Bi[0][s], ar);   // += gi_r + b_ih_r + b_hh_r
            az  = MFMA(Ax[mt], Bi[1][s], az);   // += gi_z + biases
            ain = MFMA(Ax[mt], Bi[2][s], ain);  // i_n + b_ih_n (separate from h_n)
            #pragma unroll
            for (int i = 0; i < 4; ++i) {
                float r = fast_sigmoid(ar[i]);
                float z = fast_sigmoid(az[i]);
                float n = fast_tanh(ain[i] + r * (ahn[i] + bhn[s]));
                float h = n + z * (hp[mt][s][i] - n);   // (1-z)n + z h
                hp[mt][s][i] = h;
                h_aug[(mt * 16 + q * 4 + i) * HA_PITCH + cbase + s * 16 + ln16] = (_Float16)h;
            }
          }
        // stage next encoder x (writes x slots; x frags for THIS step already in regs)
        if (next_t >= 0) {
            for (int idx = tid; idx < ROWS * 6; idx += 256) {
                int r = idx / 6, c = idx - r * 6;
                h_aug[r * HA_PITCH + 128 + c] =
                    (_Float16)history[(rowbase + r) * 300 + next_t * 6 + c];
            }
        }
        __syncthreads();
    };

    auto head_step = [&](int f) {
        // head1: a1 = relu(h @ w1^T + b1)
        half8 Ahh[4][4];
        #pragma unroll
        for (int mt = 0; mt < 4; ++mt) {
            const _Float16* rp = &h_aug[(mt * 16 + ln16) * HA_PITCH];
            #pragma unroll
            for (int kt = 0; kt < 4; ++kt)
                Ahh[mt][kt] = *(const half8*)(rp + kt * 32 + q * 8);
        }
        #pragma unroll
        for (int mt = 0; mt < 4; ++mt)
          #pragma unroll
          for (int s = 0; s < 2; ++s) {
            f32x4 a = {0,0,0,0};
            #pragma unroll
            for (int kt = 0; kt < 4; ++kt)
                a = MFMA(Ahh[mt][kt], Bw1[s][kt], a);
            #pragma unroll
            for (int i = 0; i < 4; ++i) {
                float v = a[i] + b1r[s];
                v = v > 0.0f ? v : 0.0f;
                a1s[(mt * 16 + q * 4 + i) * A1_PITCH + cbase + s * 16 + ln16] = (_Float16)v;
            }
          }
        __syncthreads();  // a1 visible
        // head2: out = a1 @ w2^T + b2; wave w handles M-tile w (rows 16w..16w+15)
        f32x4 o = {0,0,0,0};
        #pragma unroll
        for (int kt = 0; kt < 4; ++kt) {
            half8 Aa = *(const half8*)&a1s[(wave * 16 + ln16) * A1_PITCH + kt * 32 + q * 8];
            o = MFMA(Aa, Bw2[kt], o);
        }
        if (ln16 < 6) {
            #pragma unroll
            for (int i = 0; i < 4; ++i) {
                int row = wave * 16 + q * 4 + i;
                float v = o[i] + b2r;
                out[(rowbase + row) * 180 + f * 6 + ln16] = v;
                h_aug[row * HA_PITCH + 128 + ln16] = (_Float16)v;  // next decoder x
            }
        }
        __syncthreads();  // x visible before next gru_step's A_x read
    };

    // encoder: 50 steps (x for decoder step 0 = history[:,49], already staged at t=48)
    #pragma unroll 1
    for (int t = 0; t < 50; ++t) gru_step(t < 49 ? t + 1 : -1);
    // decoder: 30 steps
    #pragma unroll 1
    for (int f = 0; f < 30; ++f) { gru_step(-1); head_step(f); }
}

extern "C" void kernel_launch(void* const* d_in, const int* in_sizes, int n_in,
                              void* d_out, int out_size, void* d_ws, size_t ws_size,
                              hipStream_t stream) {
    (void)in_sizes; (void)n_in; (void)d_ws; (void)ws_size; (void)out_size;
    traj_gru<<<dim3(16384 / ROWS), dim3(256), 0, stream>>>(
        (const float*)d_in[0], (const float*)d_in[1], (const float*)d_in[2],
        (const float*)d_in[3], (const float*)d_in[4], (const float*)d_in[5],
        (const float*)d_in[6], (const float*)d_in[7], (const float*)d_in[8],
        (float*)d_out);
}

// Round 2
// 295.250 us; speedup vs baseline: 1.2162x; 1.2162x over previous
//
#include <hip/hip_runtime.h>

typedef _Float16 half8 __attribute__((ext_vector_type(8)));
typedef float f32x4 __attribute__((ext_vector_type(4)));

#define ROWS 32
#define HA_PITCH 168   // 128 h + 6 x + 1 one + pad (fp16); row stride 336 B
#define A1_PITCH 136
#define HBUF (ROWS * HA_PITCH)
#define LOG2E 1.442695041f

#define MFMA(a, b, c) __builtin_amdgcn_mfma_f32_16x16x32_f16((a), (b), (c), 0, 0, 0)

__global__ __launch_bounds__(256, 2)
void traj_gru(const float* __restrict__ history,
              const float* __restrict__ w_ih, const float* __restrict__ w_hh,
              const float* __restrict__ b_ih, const float* __restrict__ b_hh,
              const float* __restrict__ w1, const float* __restrict__ b1,
              const float* __restrict__ w2, const float* __restrict__ b2,
              float* __restrict__ out)
{
    __shared__ __align__(16) _Float16 hbuf[2 * HBUF];   // ping-pong h|x|1 tiles
    __shared__ __align__(16) _Float16 a1s[ROWS * A1_PITCH];

    const int tid  = threadIdx.x;
    const int wave = tid >> 6;
    const int lane = tid & 63;
    const int ln16 = lane & 15;
    const int q    = lane >> 4;
    const int rowbase = blockIdx.x * ROWS;
    const int cbase = wave * 32;

    // init both buffers: zeros, col 134 = 1.0 (bias lane of x K-tile)
    for (int idx = tid; idx < 2 * HBUF; idx += 256) {
        int col = idx % HA_PITCH;
        hbuf[idx] = (col == 134) ? (_Float16)1.0f : (_Float16)0.0f;
    }

    // ---- persistent B fragments, gate weights PRE-SCALED ----
    // r,z: sigmoid(x) = rcp(1 + exp2(-log2e * x))      -> scale by -log2e
    // n:   tanh(x)    = 2*rcp(1 + exp2(-2log2e*x)) - 1 -> scale by -2log2e
    half8 Bh[3][2][4];
    #pragma unroll
    for (int g = 0; g < 3; ++g) {
        float sc = (g < 2) ? -LOG2E : -2.0f * LOG2E;
        #pragma unroll
        for (int s = 0; s < 2; ++s)
            #pragma unroll
            for (int kt = 0; kt < 4; ++kt) {
                int n = g * 128 + cbase + s * 16 + ln16;
                const float* p = w_hh + n * 128 + kt * 32 + q * 8;
                half8 v;
                #pragma unroll
                for (int j = 0; j < 8; ++j) v[j] = (_Float16)(p[j] * sc);
                Bh[g][s][kt] = v;
            }
    }

    half8 Bi[3][2];
    #pragma unroll
    for (int g = 0; g < 3; ++g) {
        float sc = (g < 2) ? -LOG2E : -2.0f * LOG2E;
        #pragma unroll
        for (int s = 0; s < 2; ++s) {
            int n = g * 128 + cbase + s * 16 + ln16;
            half8 v;
            #pragma unroll
            for (int j = 0; j < 8; ++j) v[j] = (_Float16)0.0f;
            if (q == 0) {
                #pragma unroll
                for (int j = 0; j < 6; ++j) v[j] = (_Float16)(w_ih[n * 6 + j] * sc);
                float bias = b_ih[n] + (g < 2 ? b_hh[n] : 0.0f);
                v[6] = (_Float16)(bias * sc);
            }
            Bi[g][s] = v;
        }
    }

    float bhn[2], b1r[2];
    #pragma unroll
    for (int s = 0; s < 2; ++s) {
        bhn[s] = b_hh[256 + cbase + s * 16 + ln16] * (-2.0f * LOG2E); // pre-scaled
        b1r[s] = b1[cbase + s * 16 + ln16];
    }

    half8 Bw1[2][4];
    #pragma unroll
    for (int s = 0; s < 2; ++s)
        #pragma unroll
        for (int kt = 0; kt < 4; ++kt) {
            int n = cbase + s * 16 + ln16;
            const float* p = w1 + n * 128 + kt * 32 + q * 8;
            half8 v;
            #pragma unroll
            for (int j = 0; j < 8; ++j) v[j] = (_Float16)p[j];
            Bw1[s][kt] = v;
        }

    half8 Bw2[4];
    #pragma unroll
    for (int kt = 0; kt < 4; ++kt) {
        half8 v;
        #pragma unroll
        for (int j = 0; j < 8; ++j) v[j] = (_Float16)0.0f;
        if (ln16 < 6) {
            const float* p = w2 + ln16 * 128 + kt * 32 + q * 8;
            #pragma unroll
            for (int j = 0; j < 8; ++j) v[j] = (_Float16)p[j];
        }
        Bw2[kt] = v;
    }
    float b2r = (ln16 < 6) ? b2[ln16] : 0.0f;

    float hp[2][2][4] = {};   // h_prev in regs (C-layout, step-invariant)

    // x staging assignment (one fp16 per thread, tid<192)
    const int  xr = tid / 6;
    const int  xc = tid - xr * 6;
    const bool xactive = tid < ROWS * 6;

    __syncthreads();

    if (xactive)   // x_0 into buf 0
        hbuf[xr * HA_PITCH + 128 + xc] = (_Float16)history[(rowbase + xr) * 300 + xc];
    __syncthreads();

    auto gru_step = [&](int p, int next_t) {
        const _Float16* hb = hbuf + p * HBUF;
        _Float16*       hn = hbuf + (p ^ 1) * HBUF;
        #pragma unroll
        for (int mt = 0; mt < 2; ++mt) {
            half8 Ah[4], Ax;
            const _Float16* rp = hb + (mt * 16 + ln16) * HA_PITCH;
            #pragma unroll
            for (int kt = 0; kt < 4; ++kt)
                Ah[kt] = *(const half8*)(rp + kt * 32 + q * 8);
            Ax = *(const half8*)(rp + 128 + q * 8);
            #pragma unroll
            for (int s = 0; s < 2; ++s) {
                f32x4 ar = {0,0,0,0}, az = {0,0,0,0}, ah = {0,0,0,0}, an = {0,0,0,0};
                #pragma unroll
                for (int kt = 0; kt < 4; ++kt) {
                    ar = MFMA(Ah[kt], Bh[0][s][kt], ar);
                    az = MFMA(Ah[kt], Bh[1][s][kt], az);
                    ah = MFMA(Ah[kt], Bh[2][s][kt], ah);
                }
                ar = MFMA(Ax, Bi[0][s], ar);   // scaled gi_r + biases
                az = MFMA(Ax, Bi[1][s], az);
                an = MFMA(Ax, Bi[2][s], an);   // scaled i_n + b_ih_n
                #pragma unroll
                for (int i = 0; i < 4; ++i) {
                    float r = __builtin_amdgcn_rcpf(1.0f + __builtin_amdgcn_exp2f(ar[i]));
                    float z = __builtin_amdgcn_rcpf(1.0f + __builtin_amdgcn_exp2f(az[i]));
                    float t = an[i] + r * (ah[i] + bhn[s]);          // pre-scaled tanh arg
                    float n = 2.0f * __builtin_amdgcn_rcpf(1.0f + __builtin_amdgcn_exp2f(t)) - 1.0f;
                    float h = n + z * (hp[mt][s][i] - n);
                    hp[mt][s][i] = h;
                    hn[(mt * 16 + q * 4 + i) * HA_PITCH + cbase + s * 16 + ln16] = (_Float16)h;
                }
            }
        }
        if (next_t >= 0 && xactive)
            hn[xr * HA_PITCH + 128 + xc] =
                (_Float16)history[(rowbase + xr) * 300 + next_t * 6 + xc];
        __syncthreads();   // single barrier per step (ping-pong removes the other)
    };

    auto head_step = [&](int f, int p) {
        const _Float16* hb = hbuf + p * HBUF;
        _Float16*       hx = hbuf + p * HBUF;
        #pragma unroll
        for (int mt = 0; mt < 2; ++mt) {
            half8 Ahh[4];
            const _Float16* rp = hb + (mt * 16 + ln16) * HA_PITCH;
            #pragma unroll
            for (int kt = 0; kt < 4; ++kt)
                Ahh[kt] = *(const half8*)(rp + kt * 32 + q * 8);
            #pragma unroll
            for (int s = 0; s < 2; ++s) {
                f32x4 a = {0,0,0,0};
                #pragma unroll
                for (int kt = 0; kt < 4; ++kt)
                    a = MFMA(Ahh[kt], Bw1[s][kt], a);
                #pragma unroll
                for (int i = 0; i < 4; ++i) {
                    float v = a[i] + b1r[s];
                    v = v > 0.0f ? v : 0.0f;
                    a1s[(mt * 16 + q * 4 + i) * A1_PITCH + cbase + s * 16 + ln16] = (_Float16)v;
                }
            }
        }
        __syncthreads();
        if (wave < 2) {    // 2 M-tiles of 16 rows; waves 2,3 idle here
            f32x4 o = {0,0,0,0};
            #pragma unroll
            for (int kt = 0; kt < 4; ++kt) {
                half8 Aa = *(const half8*)&a1s[(wave * 16 + ln16) * A1_PITCH + kt * 32 + q * 8];
                o = MFMA(Aa, Bw2[kt], o);
            }
            if (ln16 < 6) {
                #pragma unroll
                for (int i = 0; i < 4; ++i) {
                    int row = wave * 16 + q * 4 + i;
                    float v = o[i] + b2r;
                    out[(rowbase + row) * 180 + f * 6 + ln16] = v;
                    hx[row * HA_PITCH + 128 + ln16] = (_Float16)v;  // next decoder x
                }
            }
        }
        __syncthreads();
    };

    int p = 0;
    #pragma unroll 1
    for (int t = 0; t < 50; ++t) {            // t=49 stages x_49 again for decoder step 0
        gru_step(p, t < 49 ? t + 1 : 49);
        p ^= 1;
    }
    #pragma unroll 1
    for (int f = 0; f < 30; ++f) {
        gru_step(p, -1);
        p ^= 1;
        head_step(f, p);
    }
}

extern "C" void kernel_launch(void* const* d_in, const int* in_sizes, int n_in,
                              void* d_out, int out_size, void* d_ws, size_t ws_size,
                              hipStream_t stream) {
    (void)in_sizes; (void)n_in; (void)d_ws; (void)ws_size; (void)out_size;
    traj_gru<<<dim3(16384 / ROWS), dim3(256), 0, stream>>>(
        (const float*)d_in[0], (const float*)d_in[1], (const float*)d_in[2],
        (const float*)d_in[3], (const float*)d_in[4], (const float*)d_in[5],
        (const float*)d_in[6], (const float*)d_in[7], (const float*)d_in[8],
        (float*)d_out);
}

// Round 3
// 287.375 us; speedup vs baseline: 1.2495x; 1.0274x over previous
//
#include <hip/hip_runtime.h>

typedef _Float16 half8 __attribute__((ext_vector_type(8)));
typedef float f32x4 __attribute__((ext_vector_type(4)));

#define ROWS 32
#define HP 136                 // h tile pitch in halfs (128 + 8 pad)
#define HBUFSZ (ROWS * HP)
#define LOG2E 1.442695041f
#define MFMA(a, b, c) __builtin_amdgcn_mfma_f32_16x16x32_f16((a), (b), (c), 0, 0, 0)

__global__ __launch_bounds__(512, 4)
void traj_gru(const float* __restrict__ history,
              const float* __restrict__ w_ih, const float* __restrict__ w_hh,
              const float* __restrict__ b_ih, const float* __restrict__ b_hh,
              const float* __restrict__ w1, const float* __restrict__ b1,
              const float* __restrict__ w2, const float* __restrict__ b2,
              float* __restrict__ out)
{
    __shared__ __align__(16) _Float16 hbuf[2 * HBUFSZ];     // ping-pong h tiles
    __shared__ __align__(16) _Float16 xhist[50 * ROWS * 8]; // [t][row][6x|1|0] frag layout
    __shared__ __align__(16) _Float16 xdec[ROWS * 8];       // decoder x
    __shared__ __align__(16) _Float16 a1s[ROWS * HP];       // relu hidden
    __shared__ __align__(16) _Float16 w2f[4 * 4 * 16 * 8];  // w2 B-frag [kt][q][ln16][j]

    const int tid  = threadIdx.x;
    const int wave = tid >> 6;          // 0..7, owns 16 h-columns
    const int lane = tid & 63;
    const int ln16 = lane & 15;
    const int q    = lane >> 4;
    const int rowbase = blockIdx.x * ROWS;
    const int cbase = wave * 16;

    // ---- zero-init LDS regions ----
    for (int i = tid; i < 2 * HBUFSZ; i += 512) hbuf[i] = (_Float16)0;
    for (int i = tid; i < 50 * ROWS * 8; i += 512) xhist[i] = (_Float16)0;
    for (int i = tid; i < ROWS * 8; i += 512) xdec[i] = (_Float16)0;
    for (int i = tid; i < 4 * 4 * 16 * 8; i += 512) w2f[i] = (_Float16)0;
    __syncthreads();

    // ---- fill: history -> xhist (coalesced), bias lanes, w2 fragment ----
    for (int idx = tid; idx < ROWS * 300; idx += 512) {
        int r = idx / 300, rem = idx - r * 300;
        int t = rem / 6, c = rem - t * 6;
        xhist[(t * ROWS + r) * 8 + c] = (_Float16)history[(rowbase + r) * 300 + rem];
    }
    for (int idx = tid; idx < 50 * ROWS; idx += 512)
        xhist[idx * 8 + 6] = (_Float16)1.0f;          // bias lane k=6
    for (int idx = tid; idx < ROWS; idx += 512)
        xdec[idx * 8 + 6] = (_Float16)1.0f;
    for (int idx = tid; idx < 6 * 128; idx += 512) {  // w2 -> B-frag layout
        int n = idx >> 7, k = idx & 127;
        int kt = k >> 5, qq = (k >> 3) & 3, j = k & 7;
        w2f[((kt * 4 + qq) * 16 + n) * 8 + j] = (_Float16)w2[n * 128 + k];
    }

    // ---- persistent B fragments (each wave: its 16 cols, all 3 gates) ----
    // r,z pre-scaled by -log2e (sigmoid = rcp(1+exp2)); n by -2log2e (tanh = 2rcp-1)
    half8 Bh[3][4];
    #pragma unroll
    for (int g = 0; g < 3; ++g) {
        float sc = (g < 2) ? -LOG2E : -2.0f * LOG2E;
        #pragma unroll
        for (int kt = 0; kt < 4; ++kt) {
            int n = g * 128 + cbase + ln16;
            const float* p = w_hh + n * 128 + kt * 32 + q * 8;
            half8 v;
            #pragma unroll
            for (int j = 0; j < 8; ++j) v[j] = (_Float16)(p[j] * sc);
            Bh[g][kt] = v;
        }
    }
    half8 Bi[3];
    #pragma unroll
    for (int g = 0; g < 3; ++g) {
        float sc = (g < 2) ? -LOG2E : -2.0f * LOG2E;
        int n = g * 128 + cbase + ln16;
        half8 v;
        #pragma unroll
        for (int j = 0; j < 8; ++j) v[j] = (_Float16)0.0f;
        if (q == 0) {
            #pragma unroll
            for (int j = 0; j < 6; ++j) v[j] = (_Float16)(w_ih[n * 6 + j] * sc);
            v[6] = (_Float16)((b_ih[n] + (g < 2 ? b_hh[n] : 0.0f)) * sc);
        }
        Bi[g] = v;
    }
    const float bhn = b_hh[256 + cbase + ln16] * (-2.0f * LOG2E);
    half8 Bw1[4];
    #pragma unroll
    for (int kt = 0; kt < 4; ++kt) {
        int n = cbase + ln16;
        const float* p = w1 + n * 128 + kt * 32 + q * 8;
        half8 v;
        #pragma unroll
        for (int j = 0; j < 8; ++j) v[j] = (_Float16)p[j];
        Bw1[kt] = v;
    }
    const float b1r = b1[cbase + ln16];
    const float b2r = (ln16 < 6) ? b2[ln16] : 0.0f;

    float hp[2][4] = {};   // h_prev in regs (C-layout, step-invariant)

    __syncthreads();

    auto gru_step = [&](int p, const _Float16* xp) {
        const _Float16* hb = hbuf + p * HBUFSZ;
        _Float16*       hn = hbuf + (p ^ 1) * HBUFSZ;
        #pragma unroll
        for (int mt = 0; mt < 2; ++mt) {
            const _Float16* rp = hb + (mt * 16 + ln16) * HP + q * 8;
            half8 Ax = {0,0,0,0,0,0,0,0};
            if (q == 0) Ax = *(const half8*)(xp + (mt * 16 + ln16) * 8);
            f32x4 ar = {0,0,0,0}, az = {0,0,0,0}, ah = {0,0,0,0}, an = {0,0,0,0};
            half8 Acur = *(const half8*)(rp);
            #pragma unroll
            for (int kt = 0; kt < 4; ++kt) {
                half8 Anext;
                if (kt < 3) Anext = *(const half8*)(rp + (kt + 1) * 32);
                ar = MFMA(Acur, Bh[0][kt], ar);
                az = MFMA(Acur, Bh[1][kt], az);
                ah = MFMA(Acur, Bh[2][kt], ah);
                Acur = Anext;
            }
            ar = MFMA(Ax, Bi[0], ar);
            az = MFMA(Ax, Bi[1], az);
            an = MFMA(Ax, Bi[2], an);
            _Float16* wp = hn + (mt * 16 + q * 4) * HP + cbase + ln16;
            #pragma unroll
            for (int i = 0; i < 4; ++i) {
                float r = __builtin_amdgcn_rcpf(1.0f + __builtin_amdgcn_exp2f(ar[i]));
                float z = __builtin_amdgcn_rcpf(1.0f + __builtin_amdgcn_exp2f(az[i]));
                float t = an[i] + r * (ah[i] + bhn);
                float n = 2.0f * __builtin_amdgcn_rcpf(1.0f + __builtin_amdgcn_exp2f(t)) - 1.0f;
                float h = n + z * (hp[mt][i] - n);
                hp[mt][i] = h;
                wp[i * HP] = (_Float16)h;
            }
        }
        __syncthreads();
    };

    auto head_step = [&](int f, int p) {
        const _Float16* hb = hbuf + p * HBUFSZ;
        #pragma unroll
        for (int mt = 0; mt < 2; ++mt) {
            const _Float16* rp = hb + (mt * 16 + ln16) * HP + q * 8;
            f32x4 a = {0,0,0,0};
            half8 Acur = *(const half8*)(rp);
            #pragma unroll
            for (int kt = 0; kt < 4; ++kt) {
                half8 Anext;
                if (kt < 3) Anext = *(const half8*)(rp + (kt + 1) * 32);
                a = MFMA(Acur, Bw1[kt], a);
                Acur = Anext;
            }
            _Float16* wp = a1s + (mt * 16 + q * 4) * HP + cbase + ln16;
            #pragma unroll
            for (int i = 0; i < 4; ++i) {
                float v = a[i] + b1r;
                v = v > 0.0f ? v : 0.0f;
                wp[i * HP] = (_Float16)v;
            }
        }
        __syncthreads();
        if (wave < 2) {   // M-tiles 0,1 of the 32x6 output
            f32x4 o = {0,0,0,0};
            #pragma unroll
            for (int kt = 0; kt < 4; ++kt) {
                half8 Aa = *(const half8*)&a1s[(wave * 16 + ln16) * HP + kt * 32 + q * 8];
                half8 Bw = *(const half8*)&w2f[((kt * 4 + q) * 16 + ln16) * 8];
                o = MFMA(Aa, Bw, o);
            }
            if (ln16 < 6) {
                #pragma unroll
                for (int i = 0; i < 4; ++i) {
                    int row = wave * 16 + q * 4 + i;
                    float v = o[i] + b2r;
                    out[(rowbase + row) * 180 + f * 6 + ln16] = v;
                    xdec[row * 8 + ln16] = (_Float16)v;
                }
            }
        }
        __syncthreads();
    };

    int p = 0;
    #pragma unroll 1
    for (int t = 0; t < 50; ++t) { gru_step(p, xhist + t * ROWS * 8); p ^= 1; }
    #pragma unroll 1
    for (int f = 0; f < 30; ++f) {
        gru_step(p, f == 0 ? xhist + 49 * ROWS * 8 : xdec);
        p ^= 1;
        head_step(f, p);
    }
}

extern "C" void kernel_launch(void* const* d_in, const int* in_sizes, int n_in,
                              void* d_out, int out_size, void* d_ws, size_t ws_size,
                              hipStream_t stream) {
    (void)in_sizes; (void)n_in; (void)d_ws; (void)ws_size; (void)out_size;
    traj_gru<<<dim3(16384 / ROWS), dim3(512), 0, stream>>>(
        (const float*)d_in[0], (const float*)d_in[1], (const float*)d_in[2],
        (const float*)d_in[3], (const float*)d_in[4], (const float*)d_in[5],
        (const float*)d_in[6], (const float*)d_in[7], (const float*)d_in[8],
        (float*)d_out);
}

// Round 4
// 282.034 us; speedup vs baseline: 1.2732x; 1.0189x over previous
//
#include <hip/hip_runtime.h>

typedef _Float16 half8 __attribute__((ext_vector_type(8)));
typedef float f32x4 __attribute__((ext_vector_type(4)));

#define ROWS 64
#define HP 136                  // h row pitch (halfs): 128 + 8 pad, 272 B (16B aligned)
#define HBUFSZ (ROWS * HP)
#define OP 184                  // out row pitch (floats): 180 + 4 pad
#define LOG2E 1.442695041f
#define MFMA(a,b,c) __builtin_amdgcn_mfma_f32_16x16x32_f16((a),(b),(c),0,0,0)

__global__ __launch_bounds__(512, 2)
void traj_gru(const float* __restrict__ history,
              const float* __restrict__ w_ih, const float* __restrict__ w_hh,
              const float* __restrict__ b_ih, const float* __restrict__ b_hh,
              const float* __restrict__ w1, const float* __restrict__ b1,
              const float* __restrict__ w2, const float* __restrict__ b2,
              float* __restrict__ out)
{
    __shared__ __align__(16) _Float16 hbuf[2 * HBUFSZ];          // ping-pong h
    __shared__ __align__(16) unsigned char xo_u[50 * ROWS * 16]; // 51200B: xhist(enc) / outs(dec)
    __shared__ __align__(16) _Float16 xdec[ROWS * 8];
    __shared__ __align__(16) _Float16 a1s[ROWS * HP];
    __shared__ __align__(16) _Float16 w2f[4 * 4 * 16 * 8];

    _Float16* xhist = (_Float16*)xo_u;        // [t][row][8]: x0..x5 | 1 | 0
    float*    outs  = (float*)xo_u;           // [row][OP] f32, 47104 B <= 51200

    const int tid  = threadIdx.x;
    const int wave = tid >> 6;                // 0..7, owns 16 gate-cols per gate
    const int lane = tid & 63;
    const int ln16 = lane & 15;
    const int q    = lane >> 4;
    const int sw   = ln16 & 3;                // read-side K-block swizzle
    const int rowbase = blockIdx.x * ROWS;
    const int cbase = wave * 16;
    const int bblk  = wave >> 1;              // 32-col block of this wave's columns
    const int colin = ((wave & 1) << 4) | ln16;  // col within 32-block

    // ---- init LDS ----
    for (int i = tid; i < 2 * HBUFSZ; i += 512) hbuf[i] = (_Float16)0;
    for (int i = tid; i < ROWS * 8; i += 512) xdec[i] = (_Float16)0;
    for (int i = tid; i < 4 * 4 * 16 * 8; i += 512) w2f[i] = (_Float16)0;
    __syncthreads();
    // history -> xhist (coalesced read)
    for (int idx = tid; idx < ROWS * 300; idx += 512) {
        int r = idx / 300, rem = idx - r * 300;
        int t = rem / 6, c = rem - t * 6;
        xhist[(t * ROWS + r) * 8 + c] = (_Float16)history[(rowbase + r) * 300 + rem];
    }
    for (int idx = tid; idx < 50 * ROWS; idx += 512) xhist[idx * 8 + 6] = (_Float16)1.0f;
    for (int idx = tid; idx < ROWS; idx += 512)      xdec[idx * 8 + 6] = (_Float16)1.0f;
    for (int idx = tid; idx < 6 * 128; idx += 512) { // w2 -> B-frag layout
        int n = idx >> 7, k = idx & 127;
        int kt = k >> 5, qq = (k >> 3) & 3, j = k & 7;
        w2f[((kt * 4 + qq) * 16 + n) * 8 + j] = (_Float16)w2[n * 128 + k];
    }

    // ---- persistent B fragments (16-col slice per wave, all 3 gates) ----
    // r,z pre-scaled by -log2e (sigmoid = rcp(1+exp2)); n by -2log2e (tanh = 2rcp-1)
    half8 Bh[3][4];
    #pragma unroll
    for (int g = 0; g < 3; ++g) {
        float sc = (g < 2) ? -LOG2E : -2.0f * LOG2E;
        #pragma unroll
        for (int kt = 0; kt < 4; ++kt) {
            int n = g * 128 + cbase + ln16;
            const float* p = w_hh + n * 128 + kt * 32 + q * 8;
            half8 v;
            #pragma unroll
            for (int j = 0; j < 8; ++j) v[j] = (_Float16)(p[j] * sc);
            Bh[g][kt] = v;
        }
    }
    half8 Bi[3];
    #pragma unroll
    for (int g = 0; g < 3; ++g) {
        float sc = (g < 2) ? -LOG2E : -2.0f * LOG2E;
        int n = g * 128 + cbase + ln16;
        half8 v;
        #pragma unroll
        for (int j = 0; j < 8; ++j) v[j] = (_Float16)0.0f;
        if (q == 0) {
            #pragma unroll
            for (int j = 0; j < 6; ++j) v[j] = (_Float16)(w_ih[n * 6 + j] * sc);
            v[6] = (_Float16)((b_ih[n] + (g < 2 ? b_hh[n] : 0.0f)) * sc);
        }
        Bi[g] = v;
    }
    const float bhn = b_hh[256 + cbase + ln16] * (-2.0f * LOG2E);
    half8 Bw1[4];
    #pragma unroll
    for (int kt = 0; kt < 4; ++kt) {
        int n = cbase + ln16;
        const float* p = w1 + n * 128 + kt * 32 + q * 8;
        half8 v;
        #pragma unroll
        for (int j = 0; j < 8; ++j) v[j] = (_Float16)p[j];
        Bw1[kt] = v;
    }
    const float b1r = b1[cbase + ln16];
    const float b2r = (ln16 < 6) ? b2[ln16] : 0.0f;

    float hp[4][4] = {};   // h_prev per chunk (C-layout, step-invariant)

    __syncthreads();

    // ---- GRU step: 4 row-chunks, 2-deep software pipeline (MFMA(c+1) || gates(c)) ----
    auto gru_step = [&](int p, const _Float16* xp) {
        const _Float16* hb = hbuf + p * HBUFSZ;
        _Float16*       hn = hbuf + (p ^ 1) * HBUFSZ;
        half8 Ah[2][4], Ax[2];
        f32x4 ar[2], az[2], ahh[2], an[2];

        auto loadA = [&](int c, int buf) {
            const _Float16* rp = hb + (c * 16 + ln16) * HP;
            #pragma unroll
            for (int kt = 0; kt < 4; ++kt)
                Ah[buf][kt] = *(const half8*)(rp + ((kt ^ sw) << 5) + q * 8);
            half8 x = {0,0,0,0,0,0,0,0};
            if (q == 0) x = *(const half8*)(xp + (c * 16 + ln16) * 8);
            Ax[buf] = x;
        };
        auto mfmas = [&](int buf) {
            f32x4 r = {0,0,0,0}, z = {0,0,0,0}, hh = {0,0,0,0}, n = {0,0,0,0};
            #pragma unroll
            for (int kt = 0; kt < 4; ++kt) {
                r  = MFMA(Ah[buf][kt], Bh[0][kt], r);
                z  = MFMA(Ah[buf][kt], Bh[1][kt], z);
                hh = MFMA(Ah[buf][kt], Bh[2][kt], hh);
            }
            r = MFMA(Ax[buf], Bi[0], r);
            z = MFMA(Ax[buf], Bi[1], z);
            n = MFMA(Ax[buf], Bi[2], n);
            ar[buf] = r; az[buf] = z; ahh[buf] = hh; an[buf] = n;
        };

        loadA(0, 0); mfmas(0);
        #pragma unroll
        for (int c = 0; c < 4; ++c) {
            const int cb = c & 1;
            if (c < 3) { loadA(c + 1, cb ^ 1); mfmas(cb ^ 1); }
            #pragma unroll
            for (int i = 0; i < 4; ++i) {
                float r = __builtin_amdgcn_rcpf(1.0f + __builtin_amdgcn_exp2f(ar[cb][i]));
                float z = __builtin_amdgcn_rcpf(1.0f + __builtin_amdgcn_exp2f(az[cb][i]));
                float t = an[cb][i] + r * (ahh[cb][i] + bhn);
                float n = 2.0f * __builtin_amdgcn_rcpf(1.0f + __builtin_amdgcn_exp2f(t)) - 1.0f;
                float h = n + z * (hp[c][i] - n);
                hp[c][i] = h;
                hn[(c * 16 + q * 4 + i) * HP + ((bblk ^ i) << 5) + colin] = (_Float16)h;
            }
        }
        __syncthreads();
    };

    auto head_step = [&](int f, int p) {
        const _Float16* hb = hbuf + p * HBUFSZ;
        half8 Ah[2][4];
        f32x4 aa[2];
        auto loadA = [&](int c, int buf) {
            const _Float16* rp = hb + (c * 16 + ln16) * HP;
            #pragma unroll
            for (int kt = 0; kt < 4; ++kt)
                Ah[buf][kt] = *(const half8*)(rp + ((kt ^ sw) << 5) + q * 8);
        };
        auto mfh = [&](int buf) {
            f32x4 a = {0,0,0,0};
            #pragma unroll
            for (int kt = 0; kt < 4; ++kt) a = MFMA(Ah[buf][kt], Bw1[kt], a);
            aa[buf] = a;
        };
        loadA(0, 0); mfh(0);
        #pragma unroll
        for (int c = 0; c < 4; ++c) {
            const int cb = c & 1;
            if (c < 3) { loadA(c + 1, cb ^ 1); mfh(cb ^ 1); }
            #pragma unroll
            for (int i = 0; i < 4; ++i) {
                float v = aa[cb][i] + b1r;
                v = v > 0.0f ? v : 0.0f;
                a1s[(c * 16 + q * 4 + i) * HP + ((bblk ^ i) << 5) + colin] = (_Float16)v;
            }
        }
        __syncthreads();
        if (wave < 4) {   // 4 M-tiles of the 64x6 output
            const _Float16* rp = a1s + (wave * 16 + ln16) * HP;
            f32x4 o = {0,0,0,0};
            #pragma unroll
            for (int kt = 0; kt < 4; ++kt) {
                half8 Aa = *(const half8*)(rp + ((kt ^ sw) << 5) + q * 8);
                half8 Bw = *(const half8*)&w2f[((kt * 4 + q) * 16 + ln16) * 8];
                o = MFMA(Aa, Bw, o);
            }
            if (ln16 < 6) {
                #pragma unroll
                for (int i = 0; i < 4; ++i) {
                    int row = wave * 16 + q * 4 + i;
                    float v = o[i] + b2r;
                    outs[row * OP + f * 6 + ln16] = v;
                    xdec[row * 8 + ln16] = (_Float16)v;   // next decoder x
                }
            }
        }
        __syncthreads();
    };

    int p = 0;
    #pragma unroll 1
    for (int t = 0; t < 50; ++t) { gru_step(p, xhist + t * ROWS * 8); p ^= 1; }
    #pragma unroll 1
    for (int f = 0; f < 30; ++f) {
        gru_step(p, f == 0 ? xhist + 49 * ROWS * 8 : xdec);
        p ^= 1;
        head_step(f, p);
    }

    // contiguous full-line flush of the block's 64x180 output tile
    for (int idx = tid; idx < ROWS * 180; idx += 512) {
        int r = idx / 180, j = idx - r * 180;
        out[(rowbase + r) * 180 + j] = outs[r * OP + j];
    }
}

extern "C" void kernel_launch(void* const* d_in, const int* in_sizes, int n_in,
                              void* d_out, int out_size, void* d_ws, size_t ws_size,
                              hipStream_t stream) {
    (void)in_sizes; (void)n_in; (void)d_ws; (void)ws_size; (void)out_size;
    traj_gru<<<dim3(16384 / ROWS), dim3(512), 0, stream>>>(
        (const float*)d_in[0], (const float*)d_in[1], (const float*)d_in[2],
        (const float*)d_in[3], (const float*)d_in[4], (const float*)d_in[5],
        (const float*)d_in[6], (const float*)d_in[7], (const float*)d_in[8],
        (float*)d_out);
}